// Round 5
// baseline (557.132 us; speedup 1.0000x reference)
//
#include <hip/hip_runtime.h>
#include <hip/hip_bf16.h>

#define TSTEPS 300
#define INDIM  38
#define NB     16

typedef __attribute__((ext_vector_type(4))) float    float4_;
typedef __attribute__((ext_vector_type(8))) short    short8;
typedef unsigned short ushort_;

__device__ __forceinline__ float frcp(float x){ return __builtin_amdgcn_rcpf(x); }
__device__ __forceinline__ float fsig(float x){ return frcp(1.0f + exp2f(-1.44269504f*x)); }
__device__ __forceinline__ float ftanh(float x){ return 1.0f - 2.0f*frcp(1.0f + exp2f(2.88539008f*x)); }
__device__ __forceinline__ unsigned bf16rne(float f){
    unsigned u = __float_as_uint(f);
    return (u + 0x7FFFu + ((u>>16)&1u)) >> 16;
}
// frag-native position of k-element rel (0..31) within a 32-k tile:
// lane-group g holds pos 8g..8g+7 = k {4g..4g+3, 16+4g..16+4g+3}
__device__ __forceinline__ int posk(int rel){ return 8*((rel&15)>>2) + (rel&3) + 4*(rel>>4); }
__device__ __forceinline__ short8 ldf(const ushort_* p){ return *(const short8*)p; }
__device__ __forceinline__ float4_ bmfma(short8 a, short8 b, float4_ c){
    return __builtin_amdgcn_mfma_f32_16x16x32_bf16(a, b, c, 0, 0, 0);
}

// 512 threads = 8 waves. Waves 0-3: layer1 (tiles {wv, wv+4} of 8).
// Waves 4-7: layer2 (tiles wv4:{0,1}, wv5:{2}, wv6:{3}, wv7:{4}) + x staging (wv5-7).
// Combined L1 input k': 0..31 = h1, 32..69 = x. L2 input k': 0..31 = h1, 32..51 = h2.
// inA (h1|x) and h2A double-buffered; z1s/z2s fp32 gate round-trip for cell rebalancing.
__global__ __launch_bounds__(512,2) void rnn_kernel(
    const float* __restrict__ x,
    const float* __restrict__ Wf1, const float* __restrict__ bf1,
    const float* __restrict__ Wf2, const float* __restrict__ bf2,
    const float* __restrict__ Wb1, const float* __restrict__ bb1,
    const float* __restrict__ Wb2, const float* __restrict__ bb2,
    float* __restrict__ featws)
{
    __shared__ __attribute__((aligned(16))) ushort_ W1Fh[8][16][96], W1Fl[8][16][96];
    __shared__ __attribute__((aligned(16))) ushort_ W2Fh[5][16][64], W2Fl[5][16][64];
    __shared__ __attribute__((aligned(16))) ushort_ inAh[2][16][104], inAl[2][16][104];
    __shared__ __attribute__((aligned(16))) ushort_ h2Ah[2][16][40],  h2Al[2][16][40];
    __shared__ float z1s[16][132];
    __shared__ float z2s[16][84];

    const int tid = threadIdx.x;
    const int dir = blockIdx.y;
    const int b0  = blockIdx.x * NB;

    const float* W1s = dir ? Wb1 : Wf1;
    const float* b1s = dir ? bb1 : bf1;
    const float* W2s = dir ? Wb2 : Wf2;
    const float* b2s = dir ? bb2 : bf2;

    // ---------------- zero-init (pads must be 0) ----------------
    for (int idx = tid; idx < 8*16*96;  idx += 512){ ((ushort_*)W1Fh)[idx]=0; ((ushort_*)W1Fl)[idx]=0; }
    for (int idx = tid; idx < 5*16*64;  idx += 512){ ((ushort_*)W2Fh)[idx]=0; ((ushort_*)W2Fl)[idx]=0; }
    for (int idx = tid; idx < 2*16*104; idx += 512){ ((ushort_*)inAh)[idx]=0; ((ushort_*)inAl)[idx]=0; }
    for (int idx = tid; idx < 2*16*40;  idx += 512){ ((ushort_*)h2Ah)[idx]=0; ((ushort_*)h2Al)[idx]=0; }
    __syncthreads();
    // ---------------- stage weights (frag-native, hi/lo) ----------------
    for (int idx = tid; idx < 70*128; idx += 512){
        int k = idx>>7, col = idx&127;
        int kp = (k < INDIM) ? (k + 32) : (k - INDIM);   // [h1 | x] combined order
        int off = col*96 + (kp>>5)*32 + posk(kp&31);
        float w = W1s[idx];
        unsigned hu = bf16rne(w);
        unsigned lu = bf16rne(w - __uint_as_float(hu<<16));
        ((ushort_*)W1Fh)[off] = (ushort_)hu; ((ushort_*)W1Fl)[off] = (ushort_)lu;
    }
    for (int idx = tid; idx < 52*80; idx += 512){
        int k = idx/80, col = idx%80;
        int off = col*64 + (k>>5)*32 + posk(k&31);
        float w = W2s[idx];
        unsigned hu = bf16rne(w);
        unsigned lu = bf16rne(w - __uint_as_float(hu<<16));
        ((ushort_*)W2Fh)[off] = (ushort_)hu; ((ushort_*)W2Fl)[off] = (ushort_)lu;
    }
    {   // x(0) -> inA buffer 1
        int t0 = dir ? (TSTEPS-1) : 0;
        for (int idx = tid; idx < NB*INDIM; idx += 512){
            int b = idx / INDIM, k = idx % INDIM;
            int kp = 32 + k;
            int off = (16 + b)*104 + (kp>>5)*32 + posk(kp&31);
            float w = x[((size_t)(b0+b)*TSTEPS + t0)*INDIM + k];
            unsigned hu = bf16rne(w);
            unsigned lu = bf16rne(w - __uint_as_float(hu<<16));
            ((ushort_*)inAh)[off] = (ushort_)hu; ((ushort_*)inAl)[off] = (ushort_)lu;
        }
    }
    __syncthreads();

    const int wv = tid >> 6;
    const int ln = tid & 63;
    const int g  = ln >> 4;
    const int cl = ln & 15;
    const int g8 = 8*g;

    // ---------------- B-fragments into registers ----------------
    short8 B1h[2][3], B1l[2][3];
    short8 B2h[2][2], B2l[2][2];
    if (wv < 4){
        #pragma unroll
        for (int q = 0; q < 2; ++q){
            int t = wv + 4*q;
            #pragma unroll
            for (int kt = 0; kt < 3; ++kt){
                B1h[q][kt] = ldf(&W1Fh[t][cl][kt*32 + g8]);
                B1l[q][kt] = ldf(&W1Fl[t][cl][kt*32 + g8]);
            }
        }
    } else {
        const int nT2 = (wv==4) ? 2 : 1;
        #pragma unroll
        for (int q = 0; q < 2; ++q) if (q < nT2){
            int t = (wv==4) ? q : (wv-3);
            #pragma unroll
            for (int kt = 0; kt < 2; ++kt){
                B2h[q][kt] = ldf(&W2Fh[t][cl][kt*32 + g8]);
                B2l[q][kt] = ldf(&W2Fl[t][cl][kt*32 + g8]);
            }
        }
    }

    // ---------------- cell-phase roles ----------------
    const int cb1 = tid>>5, cc1 = tid&31, posc1 = posk(cc1);
    const float bi1 = b1s[cc1], bj1 = b1s[cc1+32], bf1v = b1s[cc1+64]+1.0f, bo1 = b1s[cc1+96];
    float c1 = 0.f;
    const bool hasC2 = (ln < 40);
    const int b2c = 2*wv + (ln >= 20 ? 1 : 0);
    const int c2c = (ln < 20) ? ln : (ln - 20);
    const int posc2 = posk(c2c);
    float bi2=0.f, bj2=0.f, bf2v=0.f, bo2=0.f, c2 = 0.f;
    if (hasC2){ bi2=b2s[c2c]; bj2=b2s[c2c+20]; bf2v=b2s[c2c+40]+1.0f; bo2=b2s[c2c+60]; }

    // ---------------- x staging roles (waves 5-7) ----------------
    bool sv[4] = {false,false,false,false};
    int  sb[4] = {0,0,0,0}, soff[4] = {0,0,0,0};
    const float* sxp[4] = {x,x,x,x};
    float xr[4] = {0.f,0.f,0.f,0.f};
    const int dstep = dir ? -INDIM : INDIM;
    if (wv >= 5){
        int sid = (wv-5)*64 + ln;
        int t1 = dir ? (TSTEPS-2) : 1;
        #pragma unroll
        for (int m = 0; m < 4; ++m){
            int e = sid + 192*m;
            sv[m] = (e < NB*INDIM);
            int es = sv[m] ? e : 0;
            int b = es / INDIM, k = es % INDIM;
            int kp = 32 + k;
            sb[m] = b;
            soff[m] = (kp>>5)*32 + posk(kp&31);
            sxp[m] = x + ((size_t)(b0+b)*TSTEPS + t1)*INDIM + k;
            if (sv[m]){ xr[m] = *sxp[m]; sxp[m] += dstep; }   // preload x(1)
        }
    }

    // ---------------- main loop ----------------
    #pragma unroll 2
    for (int i = 0; i <= TSTEPS; ++i){
        const int pr = (i+1)&1;   // read buffer: h1(i-1), x(i)
        const int pw = i&1;       // write buffer: h1(i), x(i+1)
        if (wv < 4){
            if (i < TSTEPS){
                const ushort_* ah = &inAh[pr][cl][g8];
                const ushort_* al = &inAl[pr][cl][g8];
                short8 Ah0=ldf(ah), Ah1=ldf(ah+32), Ah2=ldf(ah+64);
                short8 Al0=ldf(al), Al1=ldf(al+32), Al2=ldf(al+64);
                float4_ p00{0,0,0,0}, p01{0,0,0,0}, p02{0,0,0,0};
                float4_ p10{0,0,0,0}, p11{0,0,0,0}, p12{0,0,0,0};
                p00=bmfma(Ah0,B1h[0][0],p00); p10=bmfma(Ah0,B1h[1][0],p10);
                p01=bmfma(Ah0,B1l[0][0],p01); p11=bmfma(Ah0,B1l[1][0],p11);
                p02=bmfma(Al0,B1h[0][0],p02); p12=bmfma(Al0,B1h[1][0],p12);
                p00=bmfma(Ah1,B1h[0][1],p00); p10=bmfma(Ah1,B1h[1][1],p10);
                p01=bmfma(Ah1,B1l[0][1],p01); p11=bmfma(Ah1,B1l[1][1],p11);
                p02=bmfma(Al1,B1h[0][1],p02); p12=bmfma(Al1,B1h[1][1],p12);
                p00=bmfma(Ah2,B1h[0][2],p00); p10=bmfma(Ah2,B1h[1][2],p10);
                p01=bmfma(Ah2,B1l[0][2],p01); p11=bmfma(Ah2,B1l[1][2],p11);
                p02=bmfma(Al2,B1h[0][2],p02); p12=bmfma(Al2,B1h[1][2],p12);
                float4_ z0 = p00+p01+p02, z1v = p10+p11+p12;
                #pragma unroll
                for (int r = 0; r < 4; ++r){
                    z1s[4*g+r][16*wv + cl]     = z0[r];
                    z1s[4*g+r][16*(wv+4) + cl] = z1v[r];
                }
            }
        } else {
            if (wv >= 5 && i <= TSTEPS-2){
                #pragma unroll
                for (int m = 0; m < 4; ++m) if (sv[m]){
                    unsigned hu = bf16rne(xr[m]);
                    unsigned lu = bf16rne(xr[m] - __uint_as_float(hu<<16));
                    inAh[pw][sb[m]][soff[m]] = (ushort_)hu;
                    inAl[pw][sb[m]][soff[m]] = (ushort_)lu;
                }
            }
            if (i >= 1){
                const int ph = i&1;   // h2(i-2)
                short8 Ah0 = ldf(&inAh[pr][cl][g8]);
                short8 Al0 = ldf(&inAl[pr][cl][g8]);
                short8 Ah1 = ldf(&h2Ah[ph][cl][g8]);
                short8 Al1 = ldf(&h2Al[ph][cl][g8]);
                float4_ q00{0,0,0,0}, q01{0,0,0,0}, q02{0,0,0,0};
                q00=bmfma(Ah0,B2h[0][0],q00); q01=bmfma(Ah0,B2l[0][0],q01); q02=bmfma(Al0,B2h[0][0],q02);
                q00=bmfma(Ah1,B2h[0][1],q00); q01=bmfma(Ah1,B2l[0][1],q01); q02=bmfma(Al1,B2h[0][1],q02);
                float4_ zq0 = q00+q01+q02;
                const int t0i = (wv==4) ? 0 : (wv-3);
                #pragma unroll
                for (int r = 0; r < 4; ++r) z2s[4*g+r][16*t0i + cl] = zq0[r];
                if (wv == 4){
                    float4_ q10{0,0,0,0}, q11{0,0,0,0}, q12{0,0,0,0};
                    q10=bmfma(Ah0,B2h[1][0],q10); q11=bmfma(Ah0,B2l[1][0],q11); q12=bmfma(Al0,B2h[1][0],q12);
                    q10=bmfma(Ah1,B2h[1][1],q10); q11=bmfma(Ah1,B2l[1][1],q11); q12=bmfma(Al1,B2h[1][1],q12);
                    float4_ zq1 = q10+q11+q12;
                    #pragma unroll
                    for (int r = 0; r < 4; ++r) z2s[4*g+r][16 + cl] = zq1[r];
                }
            }
            if (wv >= 5 && i <= TSTEPS-3){
                #pragma unroll
                for (int m = 0; m < 4; ++m) if (sv[m]){ xr[m] = *sxp[m]; sxp[m] += dstep; }
            }
        }
        __syncthreads();   // barY: z1s/z2s + staged x visible
        if (i < TSTEPS){
            float zi = z1s[cb1][cc1]      + bi1;
            float zj = z1s[cb1][cc1+32]   + bj1;
            float zf = z1s[cb1][cc1+64]   + bf1v;
            float zo = z1s[cb1][cc1+96]   + bo1;
            c1 = c1*fsig(zf) + fsig(zi)*ftanh(zj);
            float h = ftanh(c1)*fsig(zo);
            unsigned hu = bf16rne(h);
            unsigned lu = bf16rne(h - __uint_as_float(hu<<16));
            inAh[pw][cb1][posc1] = (ushort_)hu;
            inAl[pw][cb1][posc1] = (ushort_)lu;
        }
        if (hasC2 && i >= 1){
            float zi = z2s[b2c][c2c]      + bi2;
            float zj = z2s[b2c][c2c+20]   + bj2;
            float zf = z2s[b2c][c2c+40]   + bf2v;
            float zo = z2s[b2c][c2c+60]   + bo2;
            c2 = c2*fsig(zf) + fsig(zi)*ftanh(zj);
            float h = ftanh(c2)*fsig(zo);
            unsigned hu = bf16rne(h);
            unsigned lu = bf16rne(h - __uint_as_float(hu<<16));
            h2Ah[pr][b2c][posc2] = (ushort_)hu;   // pw2 = (i+1)&1 = pr
            h2Al[pr][b2c][posc2] = (ushort_)lu;
            if (i == 1 || i == TSTEPS){
                int off = (i == 1) ? (dir ? 60 : 0) : (dir ? 20 : 40);
                featws[(size_t)(b0+b2c)*80 + off + c2c] = h;
            }
        }
        __syncthreads();   // barX: h1/h2/x reads done before next overwrite
    }
}

__global__ __launch_bounds__(64) void fc_kernel(
    const float* __restrict__ featws,
    const float* __restrict__ Wfc1, const float* __restrict__ bfc1,
    const float* __restrict__ Wfc2, const float* __restrict__ bfc2,
    const float* __restrict__ Wfc3, const float* __restrict__ bfc3,
    float* __restrict__ out)
{
    __shared__ float f[80];
    __shared__ float h1b[80];
    __shared__ float h2b[20];
    const int b = blockIdx.x;
    const int lane = threadIdx.x;

    for (int i = lane; i < 80; i += 64) f[i] = featws[(size_t)b*80 + i];
    __syncthreads();
    for (int j = lane; j < 80; j += 64){
        float s = bfc1[j];
        #pragma unroll 8
        for (int k = 0; k < 80; ++k) s += f[k]*Wfc1[k*80 + j];
        h1b[j] = ftanh(s);
    }
    __syncthreads();
    if (lane < 20){
        float s = bfc2[lane];
        #pragma unroll 8
        for (int k = 0; k < 80; ++k) s += h1b[k]*Wfc2[k*20 + lane];
        h2b[lane] = ftanh(s);
    }
    __syncthreads();
    if (lane < 3){
        float s = bfc3[lane];
        #pragma unroll
        for (int k = 0; k < 20; ++k) s += h2b[k]*Wfc3[k*3 + lane];
        out[(size_t)b*3 + lane] = s;
    }
}

extern "C" void kernel_launch(void* const* d_in, const int* in_sizes, int n_in,
                              void* d_out, int out_size, void* d_ws, size_t ws_size,
                              hipStream_t stream) {
    const float* x    = (const float*)d_in[0];
    const float* Wf1  = (const float*)d_in[1];
    const float* bf1  = (const float*)d_in[2];
    const float* Wf2  = (const float*)d_in[3];
    const float* bf2  = (const float*)d_in[4];
    const float* Wb1  = (const float*)d_in[5];
    const float* bb1  = (const float*)d_in[6];
    const float* Wb2  = (const float*)d_in[7];
    const float* bb2  = (const float*)d_in[8];
    const float* Wfc1 = (const float*)d_in[9];
    const float* bfc1 = (const float*)d_in[10];
    const float* Wfc2 = (const float*)d_in[11];
    const float* bfc2 = (const float*)d_in[12];
    const float* Wfc3 = (const float*)d_in[13];
    const float* bfc3 = (const float*)d_in[14];

    float* feat = (float*)d_ws; // 2048*80*4 = 655360 B

    rnn_kernel<<<dim3(2048/NB, 2), 512, 0, stream>>>(
        x, Wf1, bf1, Wf2, bf2, Wb1, bb1, Wb2, bb2, feat);
    fc_kernel<<<2048, 64, 0, stream>>>(
        feat, Wfc1, bfc1, Wfc2, bfc2, Wfc3, bfc3, (float*)d_out);
}

// Round 6
// 521.154 us; speedup vs baseline: 1.0690x; 1.0690x over previous
//
#include <hip/hip_runtime.h>
#include <hip/hip_bf16.h>

#define TSTEPS 300
#define INDIM  38
#define NB     16

typedef __attribute__((ext_vector_type(4))) float    float4_;
typedef __attribute__((ext_vector_type(2))) float    float2_;
typedef __attribute__((ext_vector_type(8))) short    short8;
typedef unsigned short ushort_;

__device__ __forceinline__ float frcp(float x){ return __builtin_amdgcn_rcpf(x); }
__device__ __forceinline__ float fsig(float x){ return frcp(1.0f + exp2f(-1.44269504f*x)); }
__device__ __forceinline__ float ftanh(float x){ return 1.0f - 2.0f*frcp(1.0f + exp2f(2.88539008f*x)); }
__device__ __forceinline__ unsigned bf16rne(float f){
    unsigned u = __float_as_uint(f);
    return (u + 0x7FFFu + ((u>>16)&1u)) >> 16;
}
// frag-native position of k-element rel (0..31) within a 32-k tile:
// lane-group g holds positions 8g..8g+7 = k {4g..4g+3, 16+4g..16+4g+3}
__device__ __forceinline__ int posk(int rel){ return 8*((rel&15)>>2) + (rel&3) + 4*(rel>>4); }
__device__ __forceinline__ short8 ldf(const ushort_* p){ return *(const short8*)p; }
__device__ __forceinline__ float4_ bmfma(short8 a, short8 b, float4_ c){
    return __builtin_amdgcn_mfma_f32_16x16x32_bf16(a, b, c, 0, 0, 0);
}
// raw barrier: drains LDS writes only — global loads stay in flight (no vmcnt(0)!)
#define BAR() do{ asm volatile("s_waitcnt lgkmcnt(0)" ::: "memory"); \
                  __builtin_amdgcn_s_barrier(); \
                  asm volatile("" ::: "memory"); }while(0)

// 256 threads = 4 waves, NB=16 batches, one direction per block, grid (128,2).
// Phase p (p=0..301), ONE barrier at phase end:
//   waves 0-1 : L1 step p   = MFMA z1(p) + in-register cell1 -> h1(p) into inA[p&1]
//   waves 2-3 : (each owns 8 batches, fully independent)
//               cell2(p-2) from z2s -> h2(p-2) -> h2A ; then MFMA z2(p-1) -> z2s
//               + x staging: write x(p+1) regs -> inA[(p+1)&1], issue loads x(p+2)
// Buffers: inA double-buffered [h1 cols 0..31 | x cols 32..95]; h2A/z2s single (within-wave).
__global__ __launch_bounds__(256,1) void rnn_kernel(
    const float* __restrict__ x,
    const float* __restrict__ Wf1, const float* __restrict__ bf1,
    const float* __restrict__ Wf2, const float* __restrict__ bf2,
    const float* __restrict__ Wb1, const float* __restrict__ bb1,
    const float* __restrict__ Wb2, const float* __restrict__ bb2,
    float* __restrict__ featws)
{
    __shared__ __attribute__((aligned(16))) ushort_ W1Fh[8][16][104], W1Fl[8][16][104];
    __shared__ __attribute__((aligned(16))) ushort_ W2Fh[5][16][72],  W2Fl[5][16][72];
    __shared__ __attribute__((aligned(16))) ushort_ inAh[2][16][104], inAl[2][16][104];
    __shared__ __attribute__((aligned(16))) ushort_ h2Ah[16][40],     h2Al[16][40];
    __shared__ float z2s[16][84];

    const int tid = threadIdx.x;
    const int dir = blockIdx.y;
    const int b0  = blockIdx.x * NB;

    const float* W1s = dir ? Wb1 : Wf1;
    const float* b1s = dir ? bb1 : bf1;
    const float* W2s = dir ? Wb2 : Wf2;
    const float* b2s = dir ? bb2 : bf2;

    // ---------------- zero-init (pads must be 0; h1(-1)=h2(-1)=0) ----------------
    for (int i = tid; i < 8*16*104; i += 256){ ((ushort_*)W1Fh)[i]=0; ((ushort_*)W1Fl)[i]=0; }
    for (int i = tid; i < 5*16*72;  i += 256){ ((ushort_*)W2Fh)[i]=0; ((ushort_*)W2Fl)[i]=0; }
    for (int i = tid; i < 2*16*104; i += 256){ ((ushort_*)inAh)[i]=0; ((ushort_*)inAl)[i]=0; }
    for (int i = tid; i < 16*40;    i += 256){ ((ushort_*)h2Ah)[i]=0; ((ushort_*)h2Al)[i]=0; }
    __syncthreads();
    // ---------------- stage weights (frag-native, hi/lo planes) ----------------
    for (int idx = tid; idx < 70*128; idx += 256){
        int k = idx >> 7, c = idx & 127;
        int kp = (k < INDIM) ? (k + 32) : (k - INDIM);   // combined order [h1(0..31) | x(32..69)]
        int off = (kp>>5)*32 + posk(kp&31);
        float w = W1s[idx];
        unsigned hu = bf16rne(w);
        unsigned lu = bf16rne(w - __uint_as_float(hu<<16));
        W1Fh[c>>4][c&15][off] = (ushort_)hu;
        W1Fl[c>>4][c&15][off] = (ushort_)lu;
    }
    for (int idx = tid; idx < 52*80; idx += 256){
        int k = idx / 80, c = idx % 80;                  // already [h1(0..31) | h2(32..51)]
        int off = (k>>5)*32 + posk(k&31);
        float w = W2s[idx];
        unsigned hu = bf16rne(w);
        unsigned lu = bf16rne(w - __uint_as_float(hu<<16));
        W2Fh[c/16][c&15][off] = (ushort_)hu;
        W2Fl[c/16][c&15][off] = (ushort_)lu;
    }
    {   // x(0) -> inA buffer 0 (x columns)
        int t0 = dir ? (TSTEPS-1) : 0;
        for (int idx = tid; idx < NB*INDIM; idx += 256){
            int b = idx / INDIM, k = idx % INDIM;
            int kp = 32 + k;
            int off = (kp>>5)*32 + posk(kp&31);
            float w = x[((size_t)(b0+b)*TSTEPS + t0)*INDIM + k];
            unsigned hu = bf16rne(w);
            unsigned lu = bf16rne(w - __uint_as_float(hu<<16));
            inAh[0][b][off] = (ushort_)hu;
            inAl[0][b][off] = (ushort_)lu;
        }
    }
    __syncthreads();

    const int wv = tid >> 6;
    const int ln = tid & 63;
    const int g  = ln >> 4;
    const int cl = ln & 15;
    const int g8 = 8*g;
    const int dstep = dir ? -INDIM : INDIM;

    if (wv < 2){
        // ================= waves 0,1 : layer 1 =================
        // gate-closed tiles {wv, wv+2, wv+4, wv+6}: q=0..3 <-> gates i,j,f,o of cell 16wv+cl
        short8 Bh[4][3], Bl[4][3];
        #pragma unroll
        for (int q = 0; q < 4; ++q){
            int t = wv + 2*q;
            #pragma unroll
            for (int kt = 0; kt < 3; ++kt){
                Bh[q][kt] = ldf(&W1Fh[t][cl][kt*32 + g8]);
                Bl[q][kt] = ldf(&W1Fl[t][cl][kt*32 + g8]);
            }
        }
        const int c  = 16*wv + cl;
        const int pc = posk(c);
        const float bi = b1s[c], bj = b1s[c+32], bfv = b1s[c+64]+1.0f, bo = b1s[c+96];
        float c1[4] = {0.f,0.f,0.f,0.f};

        #pragma unroll 2
        for (int p = 0; p <= 301; ++p){
            if (p < TSTEPS){
                const int bh = (p+1)&1;   // h1(p-1)
                const int bx = p&1;       // x(p); also h1(p) write target
                short8 Ah0 = ldf(&inAh[bh][cl][g8]),      Al0 = ldf(&inAl[bh][cl][g8]);
                short8 Ah1 = ldf(&inAh[bx][cl][32 + g8]), Al1 = ldf(&inAl[bx][cl][32 + g8]);
                short8 Ah2 = ldf(&inAh[bx][cl][64 + g8]), Al2 = ldf(&inAl[bx][cl][64 + g8]);
                float4_ acc[4] = {{0,0,0,0},{0,0,0,0},{0,0,0,0},{0,0,0,0}};
                #pragma unroll
                for (int q = 0; q < 4; ++q){
                    acc[q] = bmfma(Ah0, Bh[q][0], acc[q]);
                    acc[q] = bmfma(Ah1, Bh[q][1], acc[q]);
                    acc[q] = bmfma(Ah2, Bh[q][2], acc[q]);
                    acc[q] = bmfma(Ah0, Bl[q][0], acc[q]);
                    acc[q] = bmfma(Ah1, Bl[q][1], acc[q]);
                    acc[q] = bmfma(Ah2, Bl[q][2], acc[q]);
                    acc[q] = bmfma(Al0, Bh[q][0], acc[q]);
                    acc[q] = bmfma(Al1, Bh[q][1], acc[q]);
                    acc[q] = bmfma(Al2, Bh[q][2], acc[q]);
                }
                // in-register cell1: batches 4g+r
                #pragma unroll
                for (int r = 0; r < 4; ++r){
                    float zi = acc[0][r] + bi;
                    float zj = acc[1][r] + bj;
                    float zf = acc[2][r] + bfv;
                    float zo = acc[3][r] + bo;
                    c1[r] = c1[r]*fsig(zf) + fsig(zi)*ftanh(zj);
                    float h = ftanh(c1[r])*fsig(zo);
                    unsigned hu = bf16rne(h);
                    unsigned lu = bf16rne(h - __uint_as_float(hu<<16));
                    inAh[bx][4*g + r][pc] = (ushort_)hu;
                    inAl[bx][4*g + r][pc] = (ushort_)lu;
                }
            }
            BAR();
        }
    } else {
        // ================= waves 2,3 : layer 2 (8 batches each, self-contained) + x staging =================
        const int half = wv - 2;           // batches half*8 .. half*8+7
        short8 Bh2[5][2], Bl2[5][2];
        #pragma unroll
        for (int t = 0; t < 5; ++t){
            #pragma unroll
            for (int kt = 0; kt < 2; ++kt){
                Bh2[t][kt] = ldf(&W2Fh[t][cl][kt*32 + g8]);
                Bl2[t][kt] = ldf(&W2Fl[t][cl][kt*32 + g8]);
            }
        }
        // cell2 slots: e = ln + 64m over 8b x 20c = 160
        int  sb[3], sc[3], sp[3]; bool svv[3];
        float bi2[3], bj2[3], bf2v[3], bo2[3], c2v[3];
        #pragma unroll
        for (int m = 0; m < 3; ++m){
            int e = ln + 64*m; svv[m] = (e < 160);
            int es = svv[m] ? e : 0;
            int bl = es / 20, cc = es % 20;
            sb[m] = half*8 + bl; sc[m] = cc; sp[m] = posk(cc); c2v[m] = 0.f;
            if (svv[m]){ bi2[m]=b2s[cc]; bj2[m]=b2s[cc+20]; bf2v[m]=b2s[cc+40]+1.0f; bo2[m]=b2s[cc+60]; }
            else       { bi2[m]=bj2[m]=bf2v[m]=bo2[m]=0.f; }
        }
        // x staging slots (float2): sid over 16b x 19 pairs = 304
        int stb[3], stoff[3]; bool stv[3];
        const float* stp[3]; float2_ xr[3];
        #pragma unroll
        for (int m = 0; m < 3; ++m){
            int sid = ln + 64*half + 128*m; stv[m] = (sid < 304);
            int ss = stv[m] ? sid : 0;
            int b = ss / 19, k = 2*(ss % 19);
            int kp = 32 + k;
            stb[m] = b; stoff[m] = (kp>>5)*32 + posk(kp&31);   // even -> 4B aligned pair
            int t1 = dir ? (TSTEPS-2) : 1;
            stp[m] = x + ((size_t)(b0+b)*TSTEPS + t1)*INDIM + k;
            xr[m] = float2_{0.f,0.f};
            if (stv[m]){ xr[m] = *(const float2_*)stp[m]; stp[m] += dstep; }   // preload x(1)
        }

        #pragma unroll 2
        for (int p = 0; p <= 301; ++p){
            // ---- stage x(p+1) from regs, then issue loads x(p+2) ----
            if (p <= TSTEPS-2){
                const int bw = (p+1)&1;
                #pragma unroll
                for (int m = 0; m < 3; ++m) if (stv[m]){
                    unsigned h0 = bf16rne(xr[m].x);
                    unsigned l0 = bf16rne(xr[m].x - __uint_as_float(h0<<16));
                    unsigned h1v = bf16rne(xr[m].y);
                    unsigned l1v = bf16rne(xr[m].y - __uint_as_float(h1v<<16));
                    *(unsigned*)&inAh[bw][stb[m]][stoff[m]] = h0 | (h1v<<16);
                    *(unsigned*)&inAl[bw][stb[m]][stoff[m]] = l0 | (l1v<<16);
                }
            }
            if (p <= TSTEPS-3){
                #pragma unroll
                for (int m = 0; m < 3; ++m) if (stv[m]){ xr[m] = *(const float2_*)stp[m]; stp[m] += dstep; }
            }
            // ---- cell2 for s = p-2 (reads z2s written last phase by THIS wave) ----
            if (p >= 2){
                #pragma unroll
                for (int m = 0; m < 3; ++m) if (svv[m]){
                    int b = sb[m], cc = sc[m];
                    float zi = z2s[b][cc]    + bi2[m];
                    float zj = z2s[b][cc+20] + bj2[m];
                    float zf = z2s[b][cc+40] + bf2v[m];
                    float zo = z2s[b][cc+60] + bo2[m];
                    c2v[m] = c2v[m]*fsig(zf) + fsig(zi)*ftanh(zj);
                    float h = ftanh(c2v[m])*fsig(zo);
                    unsigned hu = bf16rne(h);
                    unsigned lu = bf16rne(h - __uint_as_float(hu<<16));
                    h2Ah[b][sp[m]] = (ushort_)hu;
                    h2Al[b][sp[m]] = (ushort_)lu;
                    if (p == 2 || p == 301){
                        int off = (p == 2) ? (dir ? 60 : 0) : (dir ? 20 : 40);
                        featws[(size_t)(b0+b)*80 + off + cc] = h;
                    }
                }
            }
            // ---- MFMA z2(s = p-1): A = [h1(p-1) | h2(p-2)] ----
            if (p >= 1 && p <= TSTEPS){
                const int bh = (p-1)&1;
                short8 Ah0 = ldf(&inAh[bh][cl][g8]), Al0 = ldf(&inAl[bh][cl][g8]);
                short8 Ah1 = ldf(&h2Ah[cl][g8]),     Al1 = ldf(&h2Al[cl][g8]);
                float4_ a2[5] = {{0,0,0,0},{0,0,0,0},{0,0,0,0},{0,0,0,0},{0,0,0,0}};
                #pragma unroll
                for (int t = 0; t < 5; ++t){
                    a2[t] = bmfma(Ah0, Bh2[t][0], a2[t]);
                    a2[t] = bmfma(Ah1, Bh2[t][1], a2[t]);
                    a2[t] = bmfma(Ah0, Bl2[t][0], a2[t]);
                    a2[t] = bmfma(Ah1, Bl2[t][1], a2[t]);
                    a2[t] = bmfma(Al0, Bh2[t][0], a2[t]);
                    a2[t] = bmfma(Al1, Bh2[t][1], a2[t]);
                }
                if ((g>>1) == half){
                    #pragma unroll
                    for (int t = 0; t < 5; ++t){
                        #pragma unroll
                        for (int r = 0; r < 4; ++r) z2s[4*g + r][16*t + cl] = a2[t][r];
                    }
                }
            }
            BAR();
        }
    }
}

__global__ __launch_bounds__(64) void fc_kernel(
    const float* __restrict__ featws,
    const float* __restrict__ Wfc1, const float* __restrict__ bfc1,
    const float* __restrict__ Wfc2, const float* __restrict__ bfc2,
    const float* __restrict__ Wfc3, const float* __restrict__ bfc3,
    float* __restrict__ out)
{
    __shared__ float f[80];
    __shared__ float h1b[80];
    __shared__ float h2b[20];
    const int b = blockIdx.x;
    const int lane = threadIdx.x;

    for (int i = lane; i < 80; i += 64) f[i] = featws[(size_t)b*80 + i];
    __syncthreads();
    for (int j = lane; j < 80; j += 64){
        float s = bfc1[j];
        #pragma unroll 8
        for (int k = 0; k < 80; ++k) s += f[k]*Wfc1[k*80 + j];
        h1b[j] = ftanh(s);
    }
    __syncthreads();
    if (lane < 20){
        float s = bfc2[lane];
        #pragma unroll 8
        for (int k = 0; k < 80; ++k) s += h1b[k]*Wfc2[k*20 + lane];
        h2b[lane] = ftanh(s);
    }
    __syncthreads();
    if (lane < 3){
        float s = bfc3[lane];
        #pragma unroll
        for (int k = 0; k < 20; ++k) s += h2b[k]*Wfc3[k*3 + lane];
        out[(size_t)b*3 + lane] = s;
    }
}

extern "C" void kernel_launch(void* const* d_in, const int* in_sizes, int n_in,
                              void* d_out, int out_size, void* d_ws, size_t ws_size,
                              hipStream_t stream) {
    const float* x    = (const float*)d_in[0];
    const float* Wf1  = (const float*)d_in[1];
    const float* bf1  = (const float*)d_in[2];
    const float* Wf2  = (const float*)d_in[3];
    const float* bf2  = (const float*)d_in[4];
    const float* Wb1  = (const float*)d_in[5];
    const float* bb1  = (const float*)d_in[6];
    const float* Wb2  = (const float*)d_in[7];
    const float* bb2  = (const float*)d_in[8];
    const float* Wfc1 = (const float*)d_in[9];
    const float* bfc1 = (const float*)d_in[10];
    const float* Wfc2 = (const float*)d_in[11];
    const float* bfc2 = (const float*)d_in[12];
    const float* Wfc3 = (const float*)d_in[13];
    const float* bfc3 = (const float*)d_in[14];

    float* feat = (float*)d_ws; // 2048*80*4 = 655360 B

    rnn_kernel<<<dim3(2048/NB, 2), 256, 0, stream>>>(
        x, Wf1, bf1, Wf2, bf2, Wb1, bb1, Wb2, bb2, feat);
    fc_kernel<<<2048, 64, 0, stream>>>(
        feat, Wfc1, bfc1, Wfc2, bfc2, Wfc3, bfc3, (float*)d_out);
}

// Round 7
// 447.960 us; speedup vs baseline: 1.2437x; 1.1634x over previous
//
#include <hip/hip_runtime.h>
#include <hip/hip_bf16.h>

#define TSTEPS 300
#define INDIM  38
#define NB     16

typedef __attribute__((ext_vector_type(4))) float    float4_;
typedef __attribute__((ext_vector_type(2))) float    float2_;
typedef __attribute__((ext_vector_type(8))) short    short8;
typedef unsigned short ushort_;

__device__ __forceinline__ float frcp(float x){ return __builtin_amdgcn_rcpf(x); }
__device__ __forceinline__ float ftanh(float x){ return 1.0f - 2.0f*frcp(1.0f + exp2f(2.88539008f*x)); }
__device__ __forceinline__ unsigned bf16rne(float f){
    unsigned u = __float_as_uint(f);
    return (u + 0x7FFFu + ((u>>16)&1u)) >> 16;
}
// frag-native position of k-element rel (0..31) within a 32-k tile
__device__ __forceinline__ int posk(int rel){ return 8*((rel&15)>>2) + (rel&3) + 4*(rel>>4); }
__device__ __forceinline__ short8 ldf(const ushort_* p){ return *(const short8*)p; }
__device__ __forceinline__ float4_ bmfma(short8 a, short8 b, float4_ c){
    return __builtin_amdgcn_mfma_f32_16x16x32_bf16(a, b, c, 0, 0, 0);
}
// unified activation: g(z) = A + B * rcp(1 + exp2(C*z + D));  sigma or tanh by constants
__device__ __forceinline__ void mkgc(float bias, bool is_tanh, float4_& K){
    if (is_tanh){ K.x = 1.f; K.y = -2.f; K.z = 2.88539008f; }
    else        { K.x = 0.f; K.y =  1.f; K.z = -1.44269504f; }
    K.w = K.z * bias;
}
__device__ __forceinline__ float gact(float z, float4_ K){
    return fmaf(K.y, frcp(1.0f + exp2f(fmaf(K.z, z, K.w))), K.x);
}
// raw barrier: drains LDS only; global loads stay in flight
#define BAR() do{ asm volatile("s_waitcnt lgkmcnt(0)" ::: "memory"); \
                  __builtin_amdgcn_s_barrier(); \
                  asm volatile("" ::: "memory"); }while(0)

// 512 threads = 8 waves, NB=16 batches, one dir per block, grid (128,2) = 256 blocks
//  -> 1 block/CU, 2 waves/SIMD, ZERO garbage work.
// Phase p (0..300), two barriers:
//  subA: wv0-3: z1(p) MFMA (gate-paired tiles {wv,wv+4}) + gate ACTIVATION -> g1s
//        wv4-7: z2(p-1) MFMA (tiles {0,1}/{2}/{3}/{4}) + activation -> z2s
//        wv5-7: also stage x(p+1) -> inX[(p+1)&1], issue loads x(p+2)
//  bar1
//  subB: ALL: cell1(p): 1 cell/thread from g1s -> h1 -> inH (single buffer)
//        wv4-7: cell2(p-1): <=2 cells/lane from z2s -> h2 -> h2A (+featws at p=1/300)
//  bar2
__global__ __launch_bounds__(512,2) void rnn_kernel(
    const float* __restrict__ x,
    const float* __restrict__ Wf1, const float* __restrict__ bf1,
    const float* __restrict__ Wf2, const float* __restrict__ bf2,
    const float* __restrict__ Wb1, const float* __restrict__ bb1,
    const float* __restrict__ Wb2, const float* __restrict__ bb2,
    float* __restrict__ featws)
{
    __shared__ __attribute__((aligned(16))) ushort_ W1Fh[8][16][104], W1Fl[8][16][104];
    __shared__ __attribute__((aligned(16))) ushort_ W2Fh[5][16][72],  W2Fl[5][16][72];
    __shared__ __attribute__((aligned(16))) ushort_ inHh[16][40],     inHl[16][40];
    __shared__ __attribute__((aligned(16))) ushort_ inXh[2][16][72],  inXl[2][16][72];
    __shared__ __attribute__((aligned(16))) ushort_ h2Ah[16][40],     h2Al[16][40];
    __shared__ float g1s[4][16][33];
    __shared__ float z2s[16][84];

    const int tid = threadIdx.x;
    const int dir = blockIdx.y;
    const int b0  = blockIdx.x * NB;

    const float* W1s = dir ? Wb1 : Wf1;
    const float* b1s = dir ? bb1 : bf1;
    const float* W2s = dir ? Wb2 : Wf2;
    const float* b2s = dir ? bb2 : bf2;

    // ---------------- zero-init ----------------
    for (int i = tid; i < 8*16*104; i += 512){ ((ushort_*)W1Fh)[i]=0; ((ushort_*)W1Fl)[i]=0; }
    for (int i = tid; i < 5*16*72;  i += 512){ ((ushort_*)W2Fh)[i]=0; ((ushort_*)W2Fl)[i]=0; }
    for (int i = tid; i < 16*40;    i += 512){ ((ushort_*)inHh)[i]=0; ((ushort_*)inHl)[i]=0;
                                               ((ushort_*)h2Ah)[i]=0; ((ushort_*)h2Al)[i]=0; }
    for (int i = tid; i < 2*16*72;  i += 512){ ((ushort_*)inXh)[i]=0; ((ushort_*)inXl)[i]=0; }
    __syncthreads();
    // ---------------- stage weights (frag-native, hi/lo planes) ----------------
    for (int idx = tid; idx < 70*128; idx += 512){
        int k = idx >> 7, c = idx & 127;
        int kp = (k < INDIM) ? (k + 32) : (k - INDIM);   // combined [h1(0..31) | x(32..95)]
        int off = (kp>>5)*32 + posk(kp&31);
        float w = W1s[idx];
        unsigned hu = bf16rne(w);
        unsigned lu = bf16rne(w - __uint_as_float(hu<<16));
        W1Fh[c>>4][c&15][off] = (ushort_)hu;
        W1Fl[c>>4][c&15][off] = (ushort_)lu;
    }
    for (int idx = tid; idx < 52*80; idx += 512){
        int k = idx / 80, c = idx % 80;                  // [h1(0..31) | h2(32..51)]
        int off = (k>>5)*32 + posk(k&31);
        float w = W2s[idx];
        unsigned hu = bf16rne(w);
        unsigned lu = bf16rne(w - __uint_as_float(hu<<16));
        W2Fh[c/16][c&15][off] = (ushort_)hu;
        W2Fl[c/16][c&15][off] = (ushort_)lu;
    }
    {   // x(0) -> inX[0]
        int t0 = dir ? (TSTEPS-1) : 0;
        for (int idx = tid; idx < NB*INDIM; idx += 512){
            int b = idx / INDIM, k = idx % INDIM;
            int off = (k>>5)*32 + posk(k&31);
            float w = x[((size_t)(b0+b)*TSTEPS + t0)*INDIM + k];
            unsigned hu = bf16rne(w);
            unsigned lu = bf16rne(w - __uint_as_float(hu<<16));
            inXh[0][b][off] = (ushort_)hu;
            inXl[0][b][off] = (ushort_)lu;
        }
    }
    __syncthreads();

    const int wv = tid >> 6;
    const int ln = tid & 63;
    const int g  = ln >> 4;
    const int cl = ln & 15;
    const int g8 = 8*g;
    const int dstep = dir ? -INDIM : INDIM;

    // ---------------- role setup ----------------
    // L1 waves (0-3)
    short8 B1h[2][3], B1l[2][3];
    float4_ K10{0,0,0,0}, K11{0,0,0,0};
    int c1col = 0;
    // z2 waves (4-7)
    short8 B2h[2][2], B2l[2][2];
    float4_ K20{0,0,0,0}, K21{0,0,0,0};
    int nt2 = 0, tb2 = 0;
    if (wv < 4){
        #pragma unroll
        for (int q = 0; q < 2; ++q){
            int t = wv + 4*q;
            #pragma unroll
            for (int kt = 0; kt < 3; ++kt){
                B1h[q][kt] = ldf(&W1Fh[t][cl][kt*32 + g8]);
                B1l[q][kt] = ldf(&W1Fl[t][cl][kt*32 + g8]);
            }
        }
        c1col = 16*(wv&1) + cl;
        int col0 = 16*wv + cl;        // i (wv 0-1) or j (wv 2-3)
        int col1 = 64 + 16*wv + cl;   // f (wv 0-1) or o (wv 2-3)
        mkgc(b1s[col0] + ((col0>>5)==2 ? 1.f:0.f), (col0>>5)==1, K10);
        mkgc(b1s[col1] + ((col1>>5)==2 ? 1.f:0.f), (col1>>5)==1, K11);
    } else {
        nt2 = (wv==4) ? 2 : 1;
        tb2 = (wv==4) ? 0 : (wv-3);
        #pragma unroll
        for (int q = 0; q < 2; ++q) if (q < nt2){
            int t = tb2 + q;
            #pragma unroll
            for (int kt = 0; kt < 2; ++kt){
                B2h[q][kt] = ldf(&W2Fh[t][cl][kt*32 + g8]);
                B2l[q][kt] = ldf(&W2Fl[t][cl][kt*32 + g8]);
            }
            int col = 16*t + cl;      // 0..79; segs of 20: i | j | f | o
            int seg = col/20;
            float4_ K; mkgc(b2s[col] + (seg==2 ? 1.f:0.f), seg==1, K);
            if (q == 0) K20 = K; else K21 = K;
        }
    }

    // cell1 role: every thread owns one (batch, cell)
    const int cb = tid >> 5;          // 0..15
    const int cc = tid & 31;          // 0..31
    const int pc1 = posk(cc);
    float c1 = 0.f;

    // cell2 role (waves 4-7): slots e = idx, idx+256 over 16*20=320
    const int idx2 = tid & 255;
    bool cv[2]; int c2b[2], c2c[2], c2p[2]; float c2s[2] = {0.f, 0.f};
    cv[0] = (wv >= 4);
    cv[1] = (wv == 4);
    #pragma unroll
    for (int m = 0; m < 2; ++m){
        int e = idx2 + 256*m; if (e >= 320) e = 0;
        c2b[m] = e / 20; c2c[m] = e % 20; c2p[m] = posk(e % 20);
    }

    // x staging role (waves 5-7): pairs, 2 slots over 16*19=304
    bool stv[2] = {false,false};
    int stb[2] = {0,0}, stoff[2] = {0,0};
    const float* stp[2] = {x, x};
    float2_ xr[2] = {{0,0},{0,0}};
    if (wv >= 5){
        int sid = (wv-5)*64 + ln;
        int t1 = dir ? (TSTEPS-2) : 1;
        #pragma unroll
        for (int m = 0; m < 2; ++m){
            int e = sid + 192*m; stv[m] = (e < 304);
            int es = stv[m] ? e : 0;
            int b = es / 19, k = 2*(es % 19);
            stb[m] = b; stoff[m] = (k>>5)*32 + posk(k&31);
            stp[m] = x + ((size_t)(b0+b)*TSTEPS + t1)*INDIM + k;
            if (stv[m]){ xr[m] = *(const float2_*)stp[m]; stp[m] += dstep; }  // preload x(1)
        }
    }

    // ---------------- main loop: 301 phases ----------------
    for (int p = 0; p <= TSTEPS; ++p){
        const int px = p & 1;
        // ======== subphase A ========
        if (wv < 4){
            if (p < TSTEPS){
                short8 Ah0 = ldf(&inHh[cl][g8]),          Al0 = ldf(&inHl[cl][g8]);
                short8 Ah1 = ldf(&inXh[px][cl][g8]),      Al1 = ldf(&inXl[px][cl][g8]);
                short8 Ah2 = ldf(&inXh[px][cl][32 + g8]), Al2 = ldf(&inXl[px][cl][32 + g8]);
                float4_ acc[2] = {{0,0,0,0},{0,0,0,0}};
                #pragma unroll
                for (int q = 0; q < 2; ++q){
                    acc[q] = bmfma(Ah0, B1h[q][0], acc[q]);
                    acc[q] = bmfma(Ah1, B1h[q][1], acc[q]);
                    acc[q] = bmfma(Ah2, B1h[q][2], acc[q]);
                    acc[q] = bmfma(Ah0, B1l[q][0], acc[q]);
                    acc[q] = bmfma(Ah1, B1l[q][1], acc[q]);
                    acc[q] = bmfma(Ah2, B1l[q][2], acc[q]);
                    acc[q] = bmfma(Al0, B1h[q][0], acc[q]);
                    acc[q] = bmfma(Al1, B1h[q][1], acc[q]);
                    acc[q] = bmfma(Al2, B1h[q][2], acc[q]);
                }
                const int s0 = wv>>1, s1 = 2 + (wv>>1);
                #pragma unroll
                for (int r = 0; r < 4; ++r) g1s[s0][4*g + r][c1col] = gact(acc[0][r], K10);
                #pragma unroll
                for (int r = 0; r < 4; ++r) g1s[s1][4*g + r][c1col] = gact(acc[1][r], K11);
            }
        } else {
            if (p >= 1){
                short8 Ah0 = ldf(&inHh[cl][g8]), Al0 = ldf(&inHl[cl][g8]);
                short8 Ah1 = ldf(&h2Ah[cl][g8]), Al1 = ldf(&h2Al[cl][g8]);
                float4_ a2[2] = {{0,0,0,0},{0,0,0,0}};
                #pragma unroll
                for (int q = 0; q < 2; ++q) if (q < nt2){
                    a2[q] = bmfma(Ah0, B2h[q][0], a2[q]);
                    a2[q] = bmfma(Ah1, B2h[q][1], a2[q]);
                    a2[q] = bmfma(Ah0, B2l[q][0], a2[q]);
                    a2[q] = bmfma(Ah1, B2l[q][1], a2[q]);
                    a2[q] = bmfma(Al0, B2h[q][0], a2[q]);
                    a2[q] = bmfma(Al1, B2h[q][1], a2[q]);
                    const int t = tb2 + q;
                    const float4_ K = q ? K21 : K20;
                    #pragma unroll
                    for (int r = 0; r < 4; ++r) z2s[4*g + r][16*t + cl] = gact(a2[q][r], K);
                }
            }
            if (wv >= 5){
                if (p <= TSTEPS-2){
                    const int bw = (p+1)&1;
                    #pragma unroll
                    for (int m = 0; m < 2; ++m) if (stv[m]){
                        unsigned h0 = bf16rne(xr[m].x);
                        unsigned l0 = bf16rne(xr[m].x - __uint_as_float(h0<<16));
                        unsigned h1v = bf16rne(xr[m].y);
                        unsigned l1v = bf16rne(xr[m].y - __uint_as_float(h1v<<16));
                        *(unsigned*)&inXh[bw][stb[m]][stoff[m]] = h0 | (h1v<<16);
                        *(unsigned*)&inXl[bw][stb[m]][stoff[m]] = l0 | (l1v<<16);
                    }
                }
                if (p <= TSTEPS-3){
                    #pragma unroll
                    for (int m = 0; m < 2; ++m) if (stv[m]){ xr[m] = *(const float2_*)stp[m]; stp[m] += dstep; }
                }
            }
        }
        BAR();  // bar1
        // ======== subphase B ========
        if (p < TSTEPS){
            float gI = g1s[0][cb][cc], gJ = g1s[1][cb][cc];
            float gF = g1s[2][cb][cc], gO = g1s[3][cb][cc];
            c1 = fmaf(c1, gF, gI*gJ);
            float h = ftanh(c1)*gO;
            unsigned hu = bf16rne(h);
            unsigned lu = bf16rne(h - __uint_as_float(hu<<16));
            inHh[cb][pc1] = (ushort_)hu;
            inHl[cb][pc1] = (ushort_)lu;
        }
        if (wv >= 4 && p >= 1){
            #pragma unroll
            for (int m = 0; m < 2; ++m) if (cv[m]){
                const int b = c2b[m], c = c2c[m];
                float gI = z2s[b][c], gJ = z2s[b][c+20], gF = z2s[b][c+40], gO = z2s[b][c+60];
                c2s[m] = fmaf(c2s[m], gF, gI*gJ);
                float h = ftanh(c2s[m])*gO;
                unsigned hu = bf16rne(h);
                unsigned lu = bf16rne(h - __uint_as_float(hu<<16));
                h2Ah[b][c2p[m]] = (ushort_)hu;
                h2Al[b][c2p[m]] = (ushort_)lu;
                if (p == 1 || p == TSTEPS){
                    int off = (p == 1) ? (dir ? 60 : 0) : (dir ? 20 : 40);
                    featws[(size_t)(b0+b)*80 + off + c] = h;
                }
            }
        }
        BAR();  // bar2
    }
}

__global__ __launch_bounds__(64) void fc_kernel(
    const float* __restrict__ featws,
    const float* __restrict__ Wfc1, const float* __restrict__ bfc1,
    const float* __restrict__ Wfc2, const float* __restrict__ bfc2,
    const float* __restrict__ Wfc3, const float* __restrict__ bfc3,
    float* __restrict__ out)
{
    __shared__ float f[80];
    __shared__ float h1b[80];
    __shared__ float h2b[20];
    const int b = blockIdx.x;
    const int lane = threadIdx.x;

    for (int i = lane; i < 80; i += 64) f[i] = featws[(size_t)b*80 + i];
    __syncthreads();
    for (int j = lane; j < 80; j += 64){
        float s = bfc1[j];
        #pragma unroll 8
        for (int k = 0; k < 80; ++k) s += f[k]*Wfc1[k*80 + j];
        h1b[j] = ftanh(s);
    }
    __syncthreads();
    if (lane < 20){
        float s = bfc2[lane];
        #pragma unroll 8
        for (int k = 0; k < 80; ++k) s += h1b[k]*Wfc2[k*20 + lane];
        h2b[lane] = ftanh(s);
    }
    __syncthreads();
    if (lane < 3){
        float s = bfc3[lane];
        #pragma unroll
        for (int k = 0; k < 20; ++k) s += h2b[k]*Wfc3[k*3 + lane];
        out[(size_t)b*3 + lane] = s;
    }
}

extern "C" void kernel_launch(void* const* d_in, const int* in_sizes, int n_in,
                              void* d_out, int out_size, void* d_ws, size_t ws_size,
                              hipStream_t stream) {
    const float* x    = (const float*)d_in[0];
    const float* Wf1  = (const float*)d_in[1];
    const float* bf1  = (const float*)d_in[2];
    const float* Wf2  = (const float*)d_in[3];
    const float* bf2  = (const float*)d_in[4];
    const float* Wb1  = (const float*)d_in[5];
    const float* bb1  = (const float*)d_in[6];
    const float* Wb2  = (const float*)d_in[7];
    const float* bb2  = (const float*)d_in[8];
    const float* Wfc1 = (const float*)d_in[9];
    const float* bfc1 = (const float*)d_in[10];
    const float* Wfc2 = (const float*)d_in[11];
    const float* bfc2 = (const float*)d_in[12];
    const float* Wfc3 = (const float*)d_in[13];
    const float* bfc3 = (const float*)d_in[14];

    float* feat = (float*)d_ws; // 2048*80*4 = 655360 B

    rnn_kernel<<<dim3(2048/NB, 2), 512, 0, stream>>>(
        x, Wf1, bf1, Wf2, bf2, Wb1, bb1, Wb2, bb2, feat);
    fc_kernel<<<2048, 64, 0, stream>>>(
        feat, Wfc1, bfc1, Wfc2, bfc2, Wfc3, bfc3, (float*)d_out);
}